// Round 1
// baseline (154.087 us; speedup 1.0000x reference)
//
#include <hip/hip_runtime.h>
#include <hip/hip_bf16.h>

typedef unsigned short u16;
typedef float f32x4 __attribute__((ext_vector_type(4)));
typedef __bf16 bf16x8 __attribute__((ext_vector_type(8)));

#define M_DIM 16384
#define IN_DIM 1024
#define OUT_DIM 1024
#define K_KNOTS 12
#define KCAT 2048   // concatenated K dimension

// ---- helpers ----
__device__ __forceinline__ u16 f2bf(float f) {
    unsigned int u = __builtin_bit_cast(unsigned int, f);
    u = u + 0x7FFFu + ((u >> 16) & 1u);   // RNE
    return (u16)(u >> 16);
}

__device__ __forceinline__ void gload_lds16(const void* g, void* l) {
    __builtin_amdgcn_global_load_lds(
        (const __attribute__((address_space(1))) unsigned int*)g,
        (__attribute__((address_space(3))) unsigned int*)l, 16, 0, 0);
}

// ---- kernel 1: per-feature knot prep (sort + sigmoid mask) ----
__global__ void prep_kernel(const float* __restrict__ grid,
                            const float* __restrict__ coeffs,
                            const float* __restrict__ alive,
                            float* __restrict__ pmc,     // [IN][12]
                            float* __restrict__ pgmin,   // [IN]
                            float* __restrict__ pscale)  // [IN]
{
    int i = blockIdx.x * blockDim.x + threadIdx.x;
    if (i >= IN_DIM) return;
    float g[K_KNOTS], c[K_KNOTS], a[K_KNOTS];
    for (int k = 0; k < K_KNOTS; ++k) {
        g[k] = grid[i * K_KNOTS + k];
        c[k] = coeffs[i * K_KNOTS + k];
        a[k] = alive[i * K_KNOTS + k];
    }
    // stable insertion sort by g (matches argsort ascending)
    for (int k = 1; k < K_KNOTS; ++k) {
        float gk = g[k], ck = c[k], ak = a[k];
        int j = k - 1;
        while (j >= 0 && g[j] > gk) {
            g[j + 1] = g[j]; c[j + 1] = c[j]; a[j + 1] = a[j]; --j;
        }
        g[j + 1] = gk; c[j + 1] = ck; a[j + 1] = ak;
    }
    for (int k = 0; k < K_KNOTS; ++k)
        pmc[i * K_KNOTS + k] = c[k] / (1.0f + expf(-a[k]));
    pgmin[i] = g[0];
    pscale[i] = (float)(K_KNOTS - 1) / fmaxf(g[K_KNOTS - 1] - g[0], 1e-6f);
}

// ---- kernel 2: pack [proj_w | res_w] into bf16 B^T (OUT x KCAT) ----
__global__ __launch_bounds__(256) void conv_w_kernel(
    const float* __restrict__ pw, const float* __restrict__ rw,
    u16* __restrict__ Bw)
{
    long t = (long)blockIdx.x * blockDim.x + threadIdx.x; // over 2M/4 quads
    long nquad = (long)OUT_DIM * KCAT / 4;
    if (t >= nquad) return;
    long o = t / (KCAT / 4);
    int j = (int)(t % (KCAT / 4)) * 4;
    const float* src = (j < IN_DIM) ? &pw[o * IN_DIM + j] : &rw[o * IN_DIM + (j - IN_DIM)];
    float4 v = *(const float4*)src;
    ushort4 u;
    u.x = f2bf(v.x); u.y = f2bf(v.y); u.z = f2bf(v.z); u.w = f2bf(v.w);
    *(ushort4*)&Bw[o * KCAT + j] = u;
}

// ---- kernel 3: build A = [spline(x) | x] in bf16 (M x 2048) ----
__global__ __launch_bounds__(256) void build_a_kernel(
    const float* __restrict__ x,
    const float* __restrict__ pmc,
    const float* __restrict__ pgmin,
    const float* __restrict__ pscale,
    u16* __restrict__ Abf)
{
    __shared__ float s_mc[IN_DIM * K_KNOTS];
    __shared__ float s_gmin[IN_DIM];
    __shared__ float s_scale[IN_DIM];
    int tid = threadIdx.x;
    for (int i = tid; i < IN_DIM * K_KNOTS; i += 256) s_mc[i] = pmc[i];
    for (int i = tid; i < IN_DIM; i += 256) { s_gmin[i] = pgmin[i]; s_scale[i] = pscale[i]; }
    __syncthreads();

    for (int r = 0; r < M_DIM / 1024; ++r) {
        int m = blockIdx.x + r * 1024;
        float4 xv = *(const float4*)&x[(long)m * IN_DIM + tid * 4];
        float xs[4] = {xv.x, xv.y, xv.z, xv.w};
        ushort4 sp_out, x_out;
        u16* spp = &sp_out.x;
        u16* xpp = &x_out.x;
        #pragma unroll
        for (int j = 0; j < 4; ++j) {
            int i = tid * 4 + j;
            float xx = xs[j];
            float xn = (xx - s_gmin[i]) * s_scale[i];
            xn = fminf(fmaxf(xn, 0.0f), (float)(K_KNOTS - 1));
            int l = (int)xn;
            if (l > K_KNOTS - 2) l = K_KNOTS - 2;
            float frac = xn - (float)l;
            float cl = s_mc[i * K_KNOTS + l];
            float cr = s_mc[i * K_KNOTS + l + 1];
            float spv = cl + frac * (cr - cl);
            spp[j] = f2bf(spv);
            xpp[j] = f2bf(xx);
        }
        *(ushort4*)&Abf[(long)m * KCAT + tid * 4] = sp_out;
        *(ushort4*)&Abf[(long)m * KCAT + IN_DIM + tid * 4] = x_out;
    }
}

// ---- kernel 4: bf16 GEMM  C(MxN) = A(MxKCAT) * Bw(NxKCAT)^T + bias ----
#define BM 128
#define BN 128
#define BK 32

__global__ __launch_bounds__(256) void gemm_kernel(
    const u16* __restrict__ A,   // M x KCAT
    const u16* __restrict__ B,   // N x KCAT (B^T layout)
    const float* __restrict__ bias,
    float* __restrict__ C)
{
    __shared__ __align__(16) u16 sA[BM * BK];
    __shared__ __align__(16) u16 sB[BN * BK];

    int tid = threadIdx.x;
    int wave = tid >> 6, lane = tid & 63;
    int nbn = OUT_DIM / BN;                    // 8
    int brow = (blockIdx.x / nbn) * BM;
    int bcol = (blockIdx.x % nbn) * BN;
    int wr = (wave >> 1) * 64;
    int wc = (wave & 1) * 64;

    f32x4 acc[4][4] = {};

    // staging slots: thread covers LDS element offsets e1 and e2 (8 bf16 each)
    int e1 = tid * 8;             // bytes tid*16
    int e2 = 2048 + tid * 8;      // bytes 4096 + tid*16
    int r1 = e1 >> 5, c1 = e1 & 31;
    int r2 = e2 >> 5, c2 = e2 & 31;

    const u16* Ag1 = A + (long)(brow + r1) * KCAT + c1;
    const u16* Ag2 = A + (long)(brow + r2) * KCAT + c2;
    const u16* Bg1 = B + (long)(bcol + r1) * KCAT + c1;
    const u16* Bg2 = B + (long)(bcol + r2) * KCAT + c2;

    int frow = lane & 15;
    int fk = (lane >> 4) * 8;

    for (int k0 = 0; k0 < KCAT; k0 += BK) {
        gload_lds16(Ag1 + k0, &sA[e1]);
        gload_lds16(Ag2 + k0, &sA[e2]);
        gload_lds16(Bg1 + k0, &sB[e1]);
        gload_lds16(Bg2 + k0, &sB[e2]);
        __syncthreads();   // drains vmcnt -> tiles ready

        bf16x8 af[4], bf[4];
        #pragma unroll
        for (int m = 0; m < 4; ++m)
            af[m] = *(const bf16x8*)&sA[(wr + m * 16 + frow) * BK + fk];
        #pragma unroll
        for (int n = 0; n < 4; ++n)
            bf[n] = *(const bf16x8*)&sB[(wc + n * 16 + frow) * BK + fk];

        #pragma unroll
        for (int m = 0; m < 4; ++m)
            #pragma unroll
            for (int n = 0; n < 4; ++n)
                acc[m][n] = __builtin_amdgcn_mfma_f32_16x16x32_bf16(
                    af[m], bf[n], acc[m][n], 0, 0, 0);

        __syncthreads();   // all waves done reading before next overwrite
    }

    // epilogue: C/D layout col = lane&15, row = (lane>>4)*4 + j  (m89-verified)
    int crow0 = brow + wr + (lane >> 4) * 4;
    int ccol0 = bcol + wc + (lane & 15);
    #pragma unroll
    for (int m = 0; m < 4; ++m) {
        #pragma unroll
        for (int n = 0; n < 4; ++n) {
            int col = ccol0 + n * 16;
            float bv = bias[col];
            #pragma unroll
            for (int j = 0; j < 4; ++j) {
                int row = crow0 + m * 16 + j;
                C[(long)row * OUT_DIM + col] = acc[m][n][j] + bv;
            }
        }
    }
}

extern "C" void kernel_launch(void* const* d_in, const int* in_sizes, int n_in,
                              void* d_out, int out_size, void* d_ws, size_t ws_size,
                              hipStream_t stream) {
    const float* x      = (const float*)d_in[0];
    const float* grid   = (const float*)d_in[1];
    const float* coeffs = (const float*)d_in[2];
    const float* alive  = (const float*)d_in[3];
    const float* proj_w = (const float*)d_in[4];
    const float* proj_b = (const float*)d_in[5];
    const float* res_w  = (const float*)d_in[6];
    float* out = (float*)d_out;

    char* w = (char*)d_ws;
    size_t a_bytes = (size_t)M_DIM * KCAT * sizeof(u16);     // 64 MiB
    size_t b_bytes = (size_t)OUT_DIM * KCAT * sizeof(u16);   // 4 MiB
    u16* Abf   = (u16*)w;
    u16* Bw    = (u16*)(w + a_bytes);
    float* pmc = (float*)(w + a_bytes + b_bytes);
    float* pgmin  = pmc + IN_DIM * K_KNOTS;
    float* pscale = pgmin + IN_DIM;

    prep_kernel<<<(IN_DIM + 255) / 256, 256, 0, stream>>>(grid, coeffs, alive,
                                                          pmc, pgmin, pscale);
    conv_w_kernel<<<(OUT_DIM * KCAT / 4 + 255) / 256, 256, 0, stream>>>(proj_w, res_w, Bw);
    build_a_kernel<<<1024, 256, 0, stream>>>(x, pmc, pgmin, pscale, Abf);
    gemm_kernel<<<(M_DIM / BM) * (OUT_DIM / BN), 256, 0, stream>>>(Abf, Bw, proj_b, out);
}

// Round 2
// 116.924 us; speedup vs baseline: 1.3178x; 1.3178x over previous
//
#include <hip/hip_runtime.h>
#include <hip/hip_bf16.h>

typedef unsigned short u16;
typedef float f32x4 __attribute__((ext_vector_type(4)));
typedef __bf16 bf16x8 __attribute__((ext_vector_type(8)));

#define M_DIM 16384
#define IN_DIM 1024
#define OUT_DIM 1024
#define K_KNOTS 12
#define KCAT 2048   // concatenated K dimension

// ---- helpers ----
__device__ __forceinline__ u16 f2bf(float f) {
    unsigned int u = __builtin_bit_cast(unsigned int, f);
    u = u + 0x7FFFu + ((u >> 16) & 1u);   // RNE
    return (u16)(u >> 16);
}

__device__ __forceinline__ void gload_lds16(const void* g, void* l) {
    __builtin_amdgcn_global_load_lds(
        (const __attribute__((address_space(1))) unsigned int*)g,
        (__attribute__((address_space(3))) unsigned int*)l, 16, 0, 0);
}

// ---- kernel 1: per-feature knot prep (sort + sigmoid mask) ----
__global__ void prep_kernel(const float* __restrict__ grid,
                            const float* __restrict__ coeffs,
                            const float* __restrict__ alive,
                            float* __restrict__ pmc,     // [IN][12]
                            float* __restrict__ pgmin,   // [IN]
                            float* __restrict__ pscale)  // [IN]
{
    int i = blockIdx.x * blockDim.x + threadIdx.x;
    if (i >= IN_DIM) return;
    float g[K_KNOTS], c[K_KNOTS], a[K_KNOTS];
    for (int k = 0; k < K_KNOTS; ++k) {
        g[k] = grid[i * K_KNOTS + k];
        c[k] = coeffs[i * K_KNOTS + k];
        a[k] = alive[i * K_KNOTS + k];
    }
    for (int k = 1; k < K_KNOTS; ++k) {
        float gk = g[k], ck = c[k], ak = a[k];
        int j = k - 1;
        while (j >= 0 && g[j] > gk) {
            g[j + 1] = g[j]; c[j + 1] = c[j]; a[j + 1] = a[j]; --j;
        }
        g[j + 1] = gk; c[j + 1] = ck; a[j + 1] = ak;
    }
    for (int k = 0; k < K_KNOTS; ++k)
        pmc[i * K_KNOTS + k] = c[k] / (1.0f + expf(-a[k]));
    pgmin[i] = g[0];
    pscale[i] = (float)(K_KNOTS - 1) / fmaxf(g[K_KNOTS - 1] - g[0], 1e-6f);
}

// ---- kernel 2: pack [proj_w | res_w] into bf16 B^T (OUT x KCAT) ----
__global__ __launch_bounds__(256) void conv_w_kernel(
    const float* __restrict__ pw, const float* __restrict__ rw,
    u16* __restrict__ Bw)
{
    long t = (long)blockIdx.x * blockDim.x + threadIdx.x;
    long nquad = (long)OUT_DIM * KCAT / 4;
    if (t >= nquad) return;
    long o = t / (KCAT / 4);
    int j = (int)(t % (KCAT / 4)) * 4;
    const float* src = (j < IN_DIM) ? &pw[o * IN_DIM + j] : &rw[o * IN_DIM + (j - IN_DIM)];
    float4 v = *(const float4*)src;
    ushort4 u;
    u.x = f2bf(v.x); u.y = f2bf(v.y); u.z = f2bf(v.z); u.w = f2bf(v.w);
    *(ushort4*)&Bw[o * KCAT + j] = u;
}

// ---- kernel 3: build A = [spline(x) | x] in bf16 (M x 2048) ----
__global__ __launch_bounds__(256) void build_a_kernel(
    const float* __restrict__ x,
    const float* __restrict__ pmc,
    const float* __restrict__ pgmin,
    const float* __restrict__ pscale,
    u16* __restrict__ Abf)
{
    __shared__ float s_mc[IN_DIM * K_KNOTS];
    __shared__ float s_gmin[IN_DIM];
    __shared__ float s_scale[IN_DIM];
    int tid = threadIdx.x;
    for (int i = tid; i < IN_DIM * K_KNOTS; i += 256) s_mc[i] = pmc[i];
    for (int i = tid; i < IN_DIM; i += 256) { s_gmin[i] = pgmin[i]; s_scale[i] = pscale[i]; }
    __syncthreads();

    for (int r = 0; r < M_DIM / 1024; ++r) {
        int m = blockIdx.x + r * 1024;
        float4 xv = *(const float4*)&x[(long)m * IN_DIM + tid * 4];
        float xs[4] = {xv.x, xv.y, xv.z, xv.w};
        ushort4 sp_out, x_out;
        u16* spp = &sp_out.x;
        u16* xpp = &x_out.x;
        #pragma unroll
        for (int j = 0; j < 4; ++j) {
            int i = tid * 4 + j;
            float xx = xs[j];
            float xn = (xx - s_gmin[i]) * s_scale[i];
            xn = fminf(fmaxf(xn, 0.0f), (float)(K_KNOTS - 1));
            int l = (int)xn;
            if (l > K_KNOTS - 2) l = K_KNOTS - 2;
            float frac = xn - (float)l;
            float cl = s_mc[i * K_KNOTS + l];
            float cr = s_mc[i * K_KNOTS + l + 1];
            float spv = cl + frac * (cr - cl);
            spp[j] = f2bf(spv);
            xpp[j] = f2bf(xx);
        }
        *(ushort4*)&Abf[(long)m * KCAT + tid * 4] = sp_out;
        *(ushort4*)&Abf[(long)m * KCAT + IN_DIM + tid * 4] = x_out;
    }
}

// ---- kernel 4: 256x256 8-phase bf16 GEMM, C = A * B^T + bias ----
// 8 waves (2M x 4N), BK=64 split as kk=0/1, double-buffered LDS (128 KiB),
// fragment-ordered LDS layout (conflict-free ds_read_b128), counted vmcnt(6).
#define TBK 64
#define NT (KCAT / TBK)   // 32

__global__ __launch_bounds__(512, 2) void gemm_kernel(
    const u16* __restrict__ A,   // M x KCAT
    const u16* __restrict__ B,   // N x KCAT (B^T layout)
    const float* __restrict__ bias,
    float* __restrict__ C)
{
    // LDS element map (u16 units):
    //   A buf b : b*16384       ; B buf b : 32768 + b*16384
    //   unit kk : +kk*8192      ; frag f  : +f*512
    //   lane slot within frag: (l&15)*32 + (l>>4)*8   (16B per lane, contiguous per frag)
    __shared__ __align__(16) u16 lds[65536];   // 128 KiB

    const int tid  = threadIdx.x;
    const int lane = tid & 63;
    const int wave = tid >> 6;
    const int wm   = wave >> 2;   // 0..1
    const int wn   = wave & 3;    // 0..3

    // bijective XCD swizzle (nwg = 256, divisible by 8)
    int wgid = (blockIdx.x & 7) * 32 + (blockIdx.x >> 3);
    const int brow = (wgid >> 2) * 256;
    const int bcol = (wgid & 3) * 256;

    // staging decode: q = pass*512 + tid ; hi=q&3, r16=(q>>2)&15, f=q>>6
    // global row = base + f*16 + r16 ; col = kk*32 + hi*8 (+k0)
    const int q0 = tid, q1 = 512 + tid;
    const int r0 = (q0 >> 6) * 16 + ((q0 >> 2) & 15), c0 = (q0 & 3) * 8;
    const int r1 = (q1 >> 6) * 16 + ((q1 >> 2) & 15), c1 = (q1 & 3) * 8;
    const u16* pA0 = A + (long)(brow + r0) * KCAT + c0;
    const u16* pA1 = A + (long)(brow + r1) * KCAT + c1;
    const u16* pB0 = B + (long)(bcol + r0) * KCAT + c0;
    const u16* pB1 = B + (long)(bcol + r1) * KCAT + c1;

    const int d0 = tid * 8;          // pass-0 LDS dest (elems) within unit
    const int d1 = 4096 + tid * 8;   // pass-1
    const int loff = (lane & 15) * 32 + (lane >> 4) * 8;

    f32x4 acc[8][4] = {};

    // prologue: stage tile 0 (units in order A0,B0,A1,B1) into buf 0
    gload_lds16(pA0,      &lds[0 + d0]);      gload_lds16(pA1,      &lds[0 + d1]);
    gload_lds16(pB0,      &lds[32768 + d0]);  gload_lds16(pB1,      &lds[32768 + d1]);
    gload_lds16(pA0 + 32, &lds[8192 + d0]);   gload_lds16(pA1 + 32, &lds[8192 + d1]);
    gload_lds16(pB0 + 32, &lds[40960 + d0]);  gload_lds16(pB1 + 32, &lds[40960 + d1]);

    #pragma unroll 1
    for (int t = 0; t < NT; ++t) {
        const int ab = (t & 1) * 16384;            // this tile's A buf
        const int bb = 32768 + (t & 1) * 16384;    // this tile's B buf
        const int oa = ((t + 1) & 1) * 16384;      // prefetch A buf
        const int ob = 32768 + ((t + 1) & 1) * 16384;
        const int kp = (t == NT - 1) ? 0 : (t + 1) * TBK;  // wrap: staged, never read

        bf16x8 af[4], bfr[4];

        // ---- phase 1: stage A(kk0,t+1) ; compute m-half 0, kk=0 ----
        gload_lds16(pA0 + kp, &lds[oa + d0]);
        gload_lds16(pA1 + kp, &lds[oa + d1]);
        asm volatile("s_waitcnt vmcnt(6)\ns_barrier" ::: "memory");
        #pragma unroll
        for (int m = 0; m < 4; ++m)
            af[m] = *(const bf16x8*)&lds[ab + (wm * 8 + m) * 512 + loff];
        #pragma unroll
        for (int n = 0; n < 4; ++n)
            bfr[n] = *(const bf16x8*)&lds[bb + (wn * 4 + n) * 512 + loff];
        asm volatile("s_waitcnt lgkmcnt(0)" ::: "memory");
        __builtin_amdgcn_s_setprio(1);
        #pragma unroll
        for (int m = 0; m < 4; ++m)
            #pragma unroll
            for (int n = 0; n < 4; ++n)
                acc[m][n] = __builtin_amdgcn_mfma_f32_16x16x32_bf16(af[m], bfr[n], acc[m][n], 0, 0, 0);
        __builtin_amdgcn_s_setprio(0);
        asm volatile("s_barrier" ::: "memory");

        // ---- phase 2: stage B(kk0,t+1) ; compute m-half 1, kk=0 (reuse bfr) ----
        gload_lds16(pB0 + kp, &lds[ob + d0]);
        gload_lds16(pB1 + kp, &lds[ob + d1]);
        asm volatile("s_barrier" ::: "memory");
        #pragma unroll
        for (int m = 0; m < 4; ++m)
            af[m] = *(const bf16x8*)&lds[ab + (wm * 8 + 4 + m) * 512 + loff];
        asm volatile("s_waitcnt lgkmcnt(0)" ::: "memory");
        __builtin_amdgcn_s_setprio(1);
        #pragma unroll
        for (int m = 0; m < 4; ++m)
            #pragma unroll
            for (int n = 0; n < 4; ++n)
                acc[4 + m][n] = __builtin_amdgcn_mfma_f32_16x16x32_bf16(af[m], bfr[n], acc[4 + m][n], 0, 0, 0);
        __builtin_amdgcn_s_setprio(0);
        asm volatile("s_barrier" ::: "memory");

        // ---- phase 3: stage A(kk1,t+1) ; compute m-half 0, kk=1 ----
        gload_lds16(pA0 + kp + 32, &lds[oa + 8192 + d0]);
        gload_lds16(pA1 + kp + 32, &lds[oa + 8192 + d1]);
        asm volatile("s_waitcnt vmcnt(6)\ns_barrier" ::: "memory");
        #pragma unroll
        for (int m = 0; m < 4; ++m)
            af[m] = *(const bf16x8*)&lds[ab + 8192 + (wm * 8 + m) * 512 + loff];
        #pragma unroll
        for (int n = 0; n < 4; ++n)
            bfr[n] = *(const bf16x8*)&lds[bb + 8192 + (wn * 4 + n) * 512 + loff];
        asm volatile("s_waitcnt lgkmcnt(0)" ::: "memory");
        __builtin_amdgcn_s_setprio(1);
        #pragma unroll
        for (int m = 0; m < 4; ++m)
            #pragma unroll
            for (int n = 0; n < 4; ++n)
                acc[m][n] = __builtin_amdgcn_mfma_f32_16x16x32_bf16(af[m], bfr[n], acc[m][n], 0, 0, 0);
        __builtin_amdgcn_s_setprio(0);
        asm volatile("s_barrier" ::: "memory");

        // ---- phase 4: stage B(kk1,t+1) ; compute m-half 1, kk=1 (reuse bfr) ----
        gload_lds16(pB0 + kp + 32, &lds[ob + 8192 + d0]);
        gload_lds16(pB1 + kp + 32, &lds[ob + 8192 + d1]);
        asm volatile("s_barrier" ::: "memory");
        #pragma unroll
        for (int m = 0; m < 4; ++m)
            af[m] = *(const bf16x8*)&lds[ab + 8192 + (wm * 8 + 4 + m) * 512 + loff];
        asm volatile("s_waitcnt lgkmcnt(0)" ::: "memory");
        __builtin_amdgcn_s_setprio(1);
        #pragma unroll
        for (int m = 0; m < 4; ++m)
            #pragma unroll
            for (int n = 0; n < 4; ++n)
                acc[4 + m][n] = __builtin_amdgcn_mfma_f32_16x16x32_bf16(af[m], bfr[n], acc[4 + m][n], 0, 0, 0);
        __builtin_amdgcn_s_setprio(0);
        asm volatile("s_barrier" ::: "memory");
    }

    // ---- epilogue ----
    const int crow0 = brow + wm * 128 + (lane >> 4) * 4;
    const int ccol0 = bcol + wn * 64 + (lane & 15);
    float bv[4];
    #pragma unroll
    for (int n = 0; n < 4; ++n) bv[n] = bias[ccol0 + n * 16];
    #pragma unroll
    for (int m = 0; m < 8; ++m) {
        #pragma unroll
        for (int n = 0; n < 4; ++n) {
            #pragma unroll
            for (int j = 0; j < 4; ++j) {
                int row = crow0 + m * 16 + j;
                C[(long)row * OUT_DIM + ccol0 + n * 16] = acc[m][n][j] + bv[n];
            }
        }
    }
}

extern "C" void kernel_launch(void* const* d_in, const int* in_sizes, int n_in,
                              void* d_out, int out_size, void* d_ws, size_t ws_size,
                              hipStream_t stream) {
    const float* x      = (const float*)d_in[0];
    const float* grid   = (const float*)d_in[1];
    const float* coeffs = (const float*)d_in[2];
    const float* alive  = (const float*)d_in[3];
    const float* proj_w = (const float*)d_in[4];
    const float* proj_b = (const float*)d_in[5];
    const float* res_w  = (const float*)d_in[6];
    float* out = (float*)d_out;

    char* w = (char*)d_ws;
    size_t a_bytes = (size_t)M_DIM * KCAT * sizeof(u16);     // 64 MiB
    size_t b_bytes = (size_t)OUT_DIM * KCAT * sizeof(u16);   // 4 MiB
    u16* Abf   = (u16*)w;
    u16* Bw    = (u16*)(w + a_bytes);
    float* pmc = (float*)(w + a_bytes + b_bytes);
    float* pgmin  = pmc + IN_DIM * K_KNOTS;
    float* pscale = pgmin + IN_DIM;

    prep_kernel<<<(IN_DIM + 255) / 256, 256, 0, stream>>>(grid, coeffs, alive,
                                                          pmc, pgmin, pscale);
    conv_w_kernel<<<(OUT_DIM * KCAT / 4 + 255) / 256, 256, 0, stream>>>(proj_w, res_w, Bw);
    build_a_kernel<<<1024, 256, 0, stream>>>(x, pmc, pgmin, pscale, Abf);
    gemm_kernel<<<(M_DIM / 256) * (OUT_DIM / 256), 512, 0, stream>>>(Abf, Bw, proj_b, out);
}